// Round 5
// baseline (549.578 us; speedup 1.0000x reference)
//
#include <hip/hip_runtime.h>
#include <stdint.h>

// out[M,N] = x[M,K] @ w_eff[N,K]^T + bias[N]
#define M_DIM 8192
#define N_DIM 4096
#define K_DIM 4096

#define BM 256
#define BN 128
#define BK 32
#define NT (K_DIM / BK)   // 128 K-tiles

typedef float v4f __attribute__((ext_vector_type(4)));
typedef __bf16 v8bf __attribute__((ext_vector_type(8)));

typedef __attribute__((address_space(3))) uint32_t lds_u32_t;
typedef const __attribute__((address_space(1))) uint32_t glb_u32_t;

__device__ inline uint16_t f2bf(float f) {
    union { float f; uint32_t u; } v; v.f = f;
    uint32_t r = v.u + 0x7fffu + ((v.u >> 16) & 1u);   // RNE
    return (uint16_t)(r >> 16);
}

// ---------------- kernel 1: x fp32 -> bf16 (unit-stride, grid-stride) ----------------
__global__ __launch_bounds__(256) void cvt_x(const float* __restrict__ x,
                                             uint16_t* __restrict__ xb,
                                             long long n4) {
    long long stride = (long long)gridDim.x * 256;
    for (long long i = (long long)blockIdx.x * 256 + threadIdx.x; i < n4; i += stride) {
        float4 a = ((const float4*)x)[i];
        union { uint16_t h[4]; uint2 u; } o;
        o.h[0] = f2bf(a.x); o.h[1] = f2bf(a.y); o.h[2] = f2bf(a.z); o.h[3] = f2bf(a.w);
        ((uint2*)xb)[i] = o.u;
    }
}

// ---------------- kernel 2: build w_eff (bf16, [N,K] = B^T layout) ----------------
__global__ __launch_bounds__(256) void make_weff(const float* __restrict__ w,
                                                 uint16_t* __restrict__ weff) {
    __shared__ double red[4];
    int row  = blockIdx.x;
    int tid  = threadIdx.x;
    int lane = tid & 63;
    int wid  = tid >> 6;

    const float* wr = w + (size_t)row * K_DIM;
    const float4* w4 = (const float4*)wr + tid * 4;
    float4 r0 = w4[0], r1 = w4[1], r2 = w4[2], r3 = w4[3];
    float v[16] = { r0.x, r0.y, r0.z, r0.w, r1.x, r1.y, r1.z, r1.w,
                    r2.x, r2.y, r2.z, r2.w, r3.x, r3.y, r3.z, r3.w };

    double s = 0.0;
#pragma unroll
    for (int j = 0; j < 16; j++) s += (double)v[j];
#pragma unroll
    for (int off = 32; off > 0; off >>= 1) s += __shfl_down(s, off);
    if (lane == 0) red[wid] = s;
    __syncthreads();
    double mu = (red[0] + red[1] + red[2] + red[3]) * (1.0 / 4096.0);
    __syncthreads();

    double sa = 0.0;
#pragma unroll
    for (int j = 0; j < 16; j++) sa += fabs((double)v[j] - mu);
#pragma unroll
    for (int off = 32; off > 0; off >>= 1) sa += __shfl_down(sa, off);
    if (lane == 0) red[wid] = sa;
    __syncthreads();
    double scale = (red[0] + red[1] + red[2] + red[3]) * (1.0 / 4096.0);

    float scf = (float)scale;
    union { uint16_t h[16]; uint4 u[2]; } o;
#pragma unroll
    for (int w2 = 0; w2 < 2; w2++) {
        int base = w2 * 8;
        int amax = 0;
        float mx = fabsf(v[base]);
#pragma unroll
        for (int j = 1; j < 8; j++) {
            float aj = fabsf(v[base + j]);
            if (aj > mx) { mx = aj; amax = j; }
        }
#pragma unroll
        for (int j = 0; j < 8; j++) {
            double wc = (double)v[base + j] - mu;
            float q = (wc > 0.0) ? scf : ((wc < 0.0) ? -scf : 0.0f);
            o.h[base + j] = f2bf((j == amax) ? v[base + j] : q);
        }
    }
    uint4* dst = (uint4*)(weff + (size_t)row * K_DIM + (size_t)tid * 16);
    dst[0] = o.u[0];
    dst[1] = o.u[1];
}

// ---------------- kernel 3: 256x128 tile, BK=32, 2 blocks/CU bf16 MFMA GEMM ----------------
// Strategy change (R5): de-lockstep via OCCUPANCY, not intra-block scheduling.
// 8 waves (4m x 2n), per-wave 64x64 out, acc[4][4] f32x4 (64 VGPR).
// LDS 48 KB/block: A [2buf][256][32], B [2buf][128][32] bf16 -> 2 blocks/CU (16 waves/CU,
// 4 waves/SIMD): co-resident block hides the other's barrier/vmcnt stalls (m97/m114 mode).
// ONE barrier per K-tile: { 8 ds_read_b128 ; stage t+1 (3 global_load_lds) ; 16 MFMA
// (compiler-placed lgkmcnt) ; vmcnt(0) ; s_barrier }. Reads complete before barrier
// arrival (MFMA consumed them), stage targets the dead buffer, vmcnt(0)+BAR publishes.
// Chunk swizzle slot = c ^ ((r>>1)&3) baked into the GLOBAL source address (LDS dest
// linear for global_load_lds); ds_read_b128 conflict-free (verified 0 in R2-R4).

__device__ inline void async_cp16(const uint16_t* g, uint16_t* lds_uniform) {
    __builtin_amdgcn_global_load_lds((glb_u32_t*)g, (lds_u32_t*)lds_uniform, 16, 0, 0);
}

__device__ __forceinline__ void load4(v8bf (&d)[4], const uint16_t* base) {
#pragma unroll
    for (int i = 0; i < 4; ++i) d[i] = *(const v8bf*)(base + i * 512);
}

#define BAR  __builtin_amdgcn_s_barrier()
#define PRIO1 __builtin_amdgcn_s_setprio(1)
#define PRIO0 __builtin_amdgcn_s_setprio(0)
#define VMWAIT(N) asm volatile("s_waitcnt vmcnt(" #N ")" ::: "memory")

// stage: A tile 256x32 (16 KB, 2 loads/thread), B tile 128x32 (8 KB, 1 load/thread)
#define STG_A(BUFV, KOFF) do { \
    async_cp16(a_s0 + (KOFF), ldsA + (BUFV) * 8192 + wid * 1024);       \
    async_cp16(a_s1 + (KOFF), ldsA + (BUFV) * 8192 + wid * 1024 + 512); \
} while (0)
#define STG_B(BUFV, KOFF) do { \
    async_cp16(b_s0 + (KOFF), ldsB + (BUFV) * 4096 + wid * 512);        \
} while (0)

// one K-tile: read frags(t, buf) -> stage(t+1, buf^1) -> 16 MFMA -> vmcnt(0) -> barrier
#define TILE1(BUFV, KNEXT)                                                     \
  {                                                                            \
    v8bf aF[4], bF[4];                                                         \
    load4(aF, rdA + (BUFV) * 8192);                                            \
    load4(bF, rdB + (BUFV) * 4096);                                            \
    STG_A(1 - (BUFV), KNEXT);                                                  \
    STG_B(1 - (BUFV), KNEXT);                                                  \
    PRIO1;                                                                     \
    _Pragma("unroll")                                                          \
    for (int fm = 0; fm < 4; ++fm)                                             \
      _Pragma("unroll")                                                        \
      for (int fn = 0; fn < 4; ++fn)                                           \
        acc[fm][fn] = __builtin_amdgcn_mfma_f32_16x16x32_bf16(aF[fm], bF[fn],  \
                                                              acc[fm][fn], 0, 0, 0); \
    PRIO0;                                                                     \
    VMWAIT(0);                                                                 \
    BAR;                                                                       \
  }

__global__ __launch_bounds__(512, 4) void gemm_bt(const uint16_t* __restrict__ A,
                                                  const uint16_t* __restrict__ B,
                                                  const float* __restrict__ bias,
                                                  float* __restrict__ C) {
    __shared__ __attribute__((aligned(128))) uint16_t ldsA[2 * 8192];   // 32 KB
    __shared__ __attribute__((aligned(128))) uint16_t ldsB[2 * 4096];   // 16 KB

    int tid  = threadIdx.x;
    int lane = tid & 63;
    int wid  = tid >> 6;          // 0..7
    int wm   = wid >> 1;          // 0..3
    int wn   = wid & 1;           // 0..1

    // XCD-bijective swizzle: nwg = 1024 (%8==0); each XCD owns 4 full M-rows of tiles
    // (A-panel 4x256 rows shared within XCD; B streamed).
    int bid = blockIdx.x;
    int swz = (bid & 7) * 128 + (bid >> 3);
    long long bm = (long long)(swz >> 5) * BM;   // 0..31
    long long bn = (long long)(swz & 31) * BN;   // 0..31

    // staging geometry: one global_load_lds = 16 rows x 64 B (linear LDS dest);
    // source chunk pre-swizzled so LDS[r][slot] holds chunk slot^((r>>1)&3)
    int srow = lane >> 2;                               // 0..15
    int scs  = (lane & 3) ^ ((srow >> 1) & 3);          // source chunk (per-lane const)
    const uint16_t* a_s0 = A + (size_t)(bm + wid * 32 +  0 + srow) * K_DIM + scs * 8;
    const uint16_t* a_s1 = A + (size_t)(bm + wid * 32 + 16 + srow) * K_DIM + scs * 8;
    const uint16_t* b_s0 = B + (size_t)(bn + wid * 16 +       srow) * K_DIM + scs * 8;

    // fragment-read geometry: lane reads row rl=lane&15, chunk c=lane>>4; slot = c^((rl>>1)&3)
    int rl   = lane & 15;
    int aoff = rl * 32 + (((lane >> 4) ^ ((rl >> 1) & 3)) * 8);
    const uint16_t* rdA = ldsA + wm * 2048 + aoff;   // + buf*8192 + fm*512
    const uint16_t* rdB = ldsB + wn * 2048 + aoff;   // + buf*4096 + fn*512

    v4f acc[4][4];
#pragma unroll
    for (int i = 0; i < 4; ++i)
#pragma unroll
        for (int j = 0; j < 4; ++j) acc[i][j] = (v4f)(0.0f);

    // prologue: stage tile 0 into buf0, publish
    STG_A(0, 0);
    STG_B(0, 0);
    VMWAIT(0);
    BAR;

    // main: 128 K-tiles, buffers alternate (compile-time); tail stage clamped (valid, unused)
#pragma clang loop unroll(disable)
    for (int it = 0; it < NT / 2; ++it) {
        int t2 = it * 2;
        int k1 = (t2 + 1) * BK;
        int k2 = (t2 + 2 < NT) ? (t2 + 2) * BK : t2 * BK;   // clamp at last iter
        TILE1(0, k1);
        TILE1(1, k2);
    }

    // epilogue: 16x16 C/D layout col = lane&15, row = (lane>>4)*4 + reg
    int cl = lane & 15;
    int ch = lane >> 4;
#pragma unroll
    for (int fn = 0; fn < 4; ++fn) {
        int n = (int)bn + wn * 64 + fn * 16 + cl;
        float bj = bias[n];
#pragma unroll
        for (int fm = 0; fm < 4; ++fm) {
            size_t rbase = (size_t)(bm + wm * 64 + fm * 16 + ch * 4) * N_DIM + n;
#pragma unroll
            for (int g = 0; g < 4; ++g)
                C[rbase + (size_t)g * N_DIM] = acc[fm][fn][g] + bj;
        }
    }
}

extern "C" void kernel_launch(void* const* d_in, const int* in_sizes, int n_in,
                              void* d_out, int out_size, void* d_ws, size_t ws_size,
                              hipStream_t stream) {
    const float* x    = (const float*)d_in[0];   // [4,2048,4096]
    const float* w    = (const float*)d_in[1];   // [4096,4096]
    const float* bias = (const float*)d_in[2];   // [4096]
    float* out = (float*)d_out;

    uint16_t* xb   = (uint16_t*)d_ws;
    uint16_t* weff = (uint16_t*)((char*)d_ws + (size_t)M_DIM * K_DIM * 2);

    long long n4 = (long long)M_DIM * K_DIM / 4;
    cvt_x<<<dim3(4096), dim3(256), 0, stream>>>(x, xb, n4);
    make_weff<<<dim3(N_DIM), dim3(256), 0, stream>>>(w, weff);
    gemm_bt<<<dim3((M_DIM / BM) * (N_DIM / BN)), dim3(512), 0, stream>>>(xb, weff, bias, out);
}